// Round 11
// baseline (467.932 us; speedup 1.0000x reference)
//
#include <hip/hip_runtime.h>
#include <math.h>

// MTGCN R24 = R23 with:
//   - pair-fill split 50/50 across gemm0 AND gemm1 tails (3907-block dispatch
//     was 3 residency rounds; fill is partially additive, so balance it over
//     both under-subscribed GEMM dispatches). partP/prank move to h8's unused
//     back half (Ar is written by gemm1's GEMM blocks concurrently with its
//     tail — old alias would race).
//   - final_scalars launch removed: last-done loss block (device atomic
//     counter + threadfence) computes the output scalars.
// Kept from R23: psr single int2 scatter (WRITE 78.8->43.4MB validated), flat
// 16-pair chunks in loss, u8 single-pass histograms, LPT loss dispatch,
// NB_H=64, fused reduce+double-scan, __expf/__logf + sub<7, fp8 128B rows,
// h fp8 [M][320], MFMA GEMMs.

typedef unsigned short ushort_t;
typedef unsigned char u8;
typedef __attribute__((ext_vector_type(8))) __bf16 bf16x8;
typedef __attribute__((ext_vector_type(8))) short s16x8;
typedef __attribute__((ext_vector_type(4))) float f32x4;
typedef __attribute__((ext_vector_type(2))) float f32x2;

#define NB_H 64
#define HW 12500   // u32 words; 4 packed u8 counters each -> covers 50000 nodes

__device__ __forceinline__ f32x4 mfma16x16x32(s16x8 a, s16x8 b, f32x4 c) {
  return __builtin_amdgcn_mfma_f32_16x16x32_bf16(
      __builtin_bit_cast(bf16x8, a), __builtin_bit_cast(bf16x8, b), c, 0, 0, 0);
}
__device__ __forceinline__ ushort_t f2bf(float f) {
  union { float f; unsigned u; } c; c.f = f;
  unsigned r = (c.u + 0x7FFFu + ((c.u >> 16) & 1u)) >> 16;
  return (ushort_t)r;
}
__device__ __forceinline__ f32x2 cvt2lo(unsigned u) {
  return __builtin_amdgcn_cvt_pk_f32_fp8((int)u, false);
}
__device__ __forceinline__ f32x2 cvt2hi(unsigned u) {
  return __builtin_amdgcn_cvt_pk_f32_fp8((int)u, true);
}
__device__ __forceinline__ u8 f2fp8(float f) {
  return (u8)(__builtin_amdgcn_cvt_pk_fp8_f32(f, 0.f, 0, false) & 0xff);
}

// =======================================================================
// MFMA GEMM; VAR==0/1 dispatches carry pair-fill tail blocks (>= gemmNB)
// =======================================================================
template<int VAR, int NT, int KTOT>
__global__ __launch_bounds__(256) void gemm_mfma(
    const ushort_t* __restrict__ A0, const ushort_t* __restrict__ A1,
    const ushort_t* __restrict__ Wt,
    const float* __restrict__ bias0, const float* __restrict__ bias1,
    const float* __restrict__ x1,
    const float* __restrict__ W3c, const float* __restrict__ b3c,
    void* __restrict__ out0, void* __restrict__ out1,
    float* __restrict__ t0g, float* __restrict__ t1g, int M,
    int gemmNB, int pfOff,
    const int* __restrict__ ep, const int* __restrict__ en, int P,
    const int* __restrict__ pptr, const unsigned* __restrict__ baseP,
    const ushort_t* __restrict__ prank, int2* __restrict__ psr)
{
  if (VAR != 2 && (int)blockIdx.x >= gemmNB) {
    // ---- pair-fill tail: psr[pos] = {na, nb|negbit}, one 8B scattered store
    const int i = ((int)blockIdx.x - gemmNB) * 256 + (int)threadIdx.x + pfOff;
    const int twoP = 2 * P;
    if (i >= twoP) return;
    const int neg = (i >= P);
    const int p = neg ? i - P : i;
    const int* ia = neg ? en : ep;
    const int na = ia[p], nbv = ia[P + p];
    const int cs2 = (twoP + NB_H - 1) / NB_H;
    const int b = i / cs2;
    const unsigned bv = baseP[(size_t)b * HW + (na >> 2)];
    const int base = (int)((bv >> ((na & 3) * 8)) & 0xffu);
    const int pos = pptr[na] + base + (int)prank[i];
    psr[pos] = make_int2(na, nbv | (neg ? (int)0x80000000 : 0));
    return;
  }
  constexpr int NF = NT / 32;
  __shared__ __align__(16) ushort_t As[64 * 40];
  __shared__ __align__(16) ushort_t Bs[NT * 40];
  __shared__ float w3s[400];
  const int tid  = threadIdx.x;
  const int lane = tid & 63, w = tid >> 6;
  const int m0 = blockIdx.x * 64;
  const int wm = (w & 1) * 32, wn = (w >> 1) * (NT / 2);
  if (VAR == 2) { for (int i = tid; i < 400; i += 256) w3s[i] = W3c[i]; }
  f32x4 acc[2][NF];
#pragma unroll
  for (int i = 0; i < 2; ++i)
#pragma unroll
    for (int j = 0; j < NF; ++j) acc[i][j] = (f32x4){0.f, 0.f, 0.f, 0.f};

  for (int k0 = 0; k0 < KTOT; k0 += 32) {
    { // A stage
      const int r = tid >> 2, c8 = (tid & 3) * 8;
      const int gm = m0 + r;
      uint4 v = {0u, 0u, 0u, 0u};
      if (gm < M) {
        if (VAR == 1) {  // fp8 h: load 8 bytes, convert to 8 bf16
          const u8* s8 = (const u8*)A0 + (size_t)gm * 320 + k0 + c8;
          const uint2 r8 = *(const uint2*)s8;
          const f32x2 f0 = cvt2lo(r8.x), f1 = cvt2hi(r8.x);
          const f32x2 f2 = cvt2lo(r8.y), f3 = cvt2hi(r8.y);
          v.x = (unsigned)f2bf(f0.x) | ((unsigned)f2bf(f0.y) << 16);
          v.y = (unsigned)f2bf(f1.x) | ((unsigned)f2bf(f1.y) << 16);
          v.z = (unsigned)f2bf(f2.x) | ((unsigned)f2bf(f2.y) << 16);
          v.w = (unsigned)f2bf(f3.x) | ((unsigned)f2bf(f3.y) << 16);
        } else {
          const ushort_t* srcp;
          if (VAR == 0) srcp = (k0 < 128) ? A0 + (size_t)gm * 128 + k0 + c8
                                          : A1 + (size_t)gm * 128 + (k0 - 128) + c8;
          else srcp = A0 + (size_t)gm * 128 + k0 + c8;
          v = *(const uint4*)srcp;
        }
      }
      *(uint4*)&As[r * 40 + c8] = v;
    }
    { // B stage
      const int c8 = (tid & 3) * 8;
#pragma unroll
      for (int i = 0; i < (NT * 4 + 255) / 256; ++i) {
        const int r = (tid >> 2) + i * 64;
        if (r < NT)
          *(uint4*)&Bs[r * 40 + c8] = *(const uint4*)(Wt + (size_t)r * KTOT + k0 + c8);
      }
    }
    __syncthreads();
    s16x8 af[2], bfr[NF];
#pragma unroll
    for (int mi = 0; mi < 2; ++mi)
      af[mi] = *(const s16x8*)&As[(wm + mi * 16 + (lane & 15)) * 40 + (lane >> 4) * 8];
#pragma unroll
    for (int ni = 0; ni < NF; ++ni)
      bfr[ni] = *(const s16x8*)&Bs[(wn + ni * 16 + (lane & 15)) * 40 + (lane >> 4) * 8];
#pragma unroll
    for (int mi = 0; mi < 2; ++mi)
#pragma unroll
      for (int ni = 0; ni < NF; ++ni)
        acc[mi][ni] = mfma16x16x32(af[mi], bfr[ni], acc[mi][ni]);
    __syncthreads();
  }

  if (VAR == 2) {
#pragma unroll
    for (int mi = 0; mi < 2; ++mi)
#pragma unroll
      for (int r = 0; r < 4; ++r) {
        const int gRow = m0 + wm + mi * 16 + ((lane >> 4) << 2) + r;
        float p0 = 0.f, p1 = 0.f, p2 = 0.f, p3 = 0.f;
#pragma unroll
        for (int ni = 0; ni < NF; ++ni) {
          const int col = wn + ni * 16 + (lane & 15);
          const float v = acc[mi][ni][r];
          if (gRow < M) {
            if (col < 100) {
              const float x2v = x1[(size_t)gRow * 128 + col] + fmaxf(v + bias0[col], 0.f);
              p0 = fmaf(x2v, w3s[col * 2 + 0], p0);
              p1 = fmaf(x2v, w3s[col * 2 + 1], p1);
              p2 = fmaf(x2v, w3s[200 + col * 2 + 0], p2);
              p3 = fmaf(x2v, w3s[200 + col * 2 + 1], p3);
            } else if (col < 200) {
              const int c = col - 100;
              ((u8*)out1)[(size_t)gRow * 128 + c] =
                  f2fp8(x1[(size_t)gRow * 128 + c] + fmaxf(v + bias1[c], 0.f));
            }
          }
        }
        if (wn == 0) {
#pragma unroll
          for (int off = 8; off; off >>= 1) {
            p0 += __shfl_down(p0, off, 16);
            p1 += __shfl_down(p1, off, 16);
            p2 += __shfl_down(p2, off, 16);
            p3 += __shfl_down(p3, off, 16);
          }
          if ((lane & 15) == 0 && gRow < M) {
            t0g[(size_t)gRow * 2 + 0] = p0 + b3c[0];
            t0g[(size_t)gRow * 2 + 1] = p1 + b3c[1];
            t1g[(size_t)gRow * 2 + 0] = p2;
            t1g[(size_t)gRow * 2 + 1] = p3;
          }
        }
      }
  } else {
#pragma unroll
    for (int mi = 0; mi < 2; ++mi)
#pragma unroll
      for (int ni = 0; ni < NF; ++ni)
#pragma unroll
        for (int r = 0; r < 4; ++r) {
          const int gRow = m0 + wm + mi * 16 + ((lane >> 4) << 2) + r;
          const int col  = wn + ni * 16 + (lane & 15);
          if (gRow >= M) continue;
          const float v = acc[mi][ni][r];
          if (VAR == 0) {
            ((u8*)out0)[(size_t)gRow * 320 + col] =
                (col < 300) ? f2fp8(fmaxf(v + bias0[col], 0.f)) : (u8)0;
          } else {
            if (col < 100) ((float*)out0)[(size_t)gRow * 128 + col] = v + bias0[col];
            else if (col < 200) ((u8*)out1)[(size_t)gRow * 128 + (col - 100)] = f2fp8(v);
          }
        }
  }
}

// =======================================================================
// prep: src-hist [0,64) | dst-hist+rank [64,128) | pair-hist+prank [128,192)
//       | packing (rest).  Single-pass u8 histograms (4 per u32 word).
// =======================================================================
__global__ __launch_bounds__(256) void prep(
    const int* __restrict__ src, const int* __restrict__ dst, int E, int M,
    unsigned* __restrict__ partS, unsigned* __restrict__ partD,
    ushort_t* __restrict__ rank,
    const int* __restrict__ ep, const int* __restrict__ en, int P,
    unsigned* __restrict__ partP, ushort_t* __restrict__ prank,
    const float* __restrict__ x, ushort_t* __restrict__ xb,
    u8* __restrict__ xf8, int n4,
    const float* __restrict__ W1, const float* __restrict__ W2,
    const float* __restrict__ l1W, const float* __restrict__ l2W,
    ushort_t* __restrict__ W1t, ushort_t* __restrict__ W2t,
    ushort_t* __restrict__ Wlt)
{
  __shared__ unsigned hist[HW];
  const int blk = blockIdx.x;
  if (blk < 2 * NB_H) {
    const int isD = (blk >= NB_H);
    const int b = isD ? blk - NB_H : blk;
    const int* keys = isD ? dst : src;
    unsigned* part = isD ? partD : partS;
    const int cs = (E + NB_H - 1) / NB_H;
    const int e0 = b * cs;
    const int e1 = (e0 + cs < E) ? e0 + cs : E;
    for (int i = threadIdx.x; i < HW; i += 256) hist[i] = 0;
    __syncthreads();
    for (int e = e0 + threadIdx.x; e < e1; e += 256) {
      const int k = keys[e];
      const unsigned old = atomicAdd(&hist[k >> 2], 1u << ((k & 3) * 8));
      if (isD) rank[e] = (ushort_t)((old >> ((k & 3) * 8)) & 0xffu);
    }
    __syncthreads();
    for (int i = threadIdx.x; i < HW; i += 256)
      part[(size_t)b * HW + i] = hist[i];
    return;
  }
  if (blk < 3 * NB_H) {
    // pair-hist keyed by first endpoint na over index space [0, 2P)
    const int b = blk - 2 * NB_H;
    const int twoP = 2 * P;
    const int cs2 = (twoP + NB_H - 1) / NB_H;
    const int e0 = b * cs2;
    const int e1 = (e0 + cs2 < twoP) ? e0 + cs2 : twoP;
    for (int i = threadIdx.x; i < HW; i += 256) hist[i] = 0;
    __syncthreads();
    for (int i = e0 + threadIdx.x; i < e1; i += 256) {
      const int neg = (i >= P);
      const int p = neg ? i - P : i;
      const int* ia = neg ? en : ep;
      const int k = ia[p];
      const unsigned old = atomicAdd(&hist[k >> 2], 1u << ((k & 3) * 8));
      prank[i] = (ushort_t)((old >> ((k & 3) * 8)) & 0xffu);
    }
    __syncthreads();
    for (int i = threadIdx.x; i < HW; i += 256)
      partP[(size_t)b * HW + i] = hist[i];
    return;
  }
  // packing section
  const int i = (blk - 3 * NB_H) * 256 + threadIdx.x;
  if (i < n4) {
    const float4 v = ((const float4*)x)[i];
    ushort4 o; o.x = f2bf(v.x); o.y = f2bf(v.y); o.z = f2bf(v.z); o.w = f2bf(v.w);
    ((ushort4*)xb)[i] = o;
    int p = 0;
    p = __builtin_amdgcn_cvt_pk_fp8_f32(v.x, v.y, p, false);
    p = __builtin_amdgcn_cvt_pk_fp8_f32(v.z, v.w, p, true);
    ((unsigned*)xf8)[i] = (unsigned)p;
    return;
  }
  const int j = i - n4;
  if (j < 81920) {                       // W1t [320][256]
    const int n = j >> 8, k = j & 255;
    float v = 0.f;
    if (n < 300) v = (k < 128) ? W1[k * 300 + n] : W1[38400 + (k - 128) * 300 + n];
    W1t[j] = f2bf(v);
  } else if (j < 153600) {               // W2t [224][320]
    const int jj = j - 81920;
    const int n = jj / 320, k = jj - n * 320;
    float v = 0.f;
    if (n < 200 && k < 300) v = W2[(n < 100 ? 0 : 30000) + k * 100 + (n % 100)];
    W2t[jj] = f2bf(v);
  } else if (j < 182272) {               // Wlt [224][128]
    const int jj = j - 153600;
    const int n = jj >> 7, k = jj & 127;
    float v = 0.f;
    if (n < 100) v = l1W[n * 128 + k];
    else if (n < 200) v = l2W[(n - 100) * 128 + k];
    Wlt[jj] = f2bf(v);
  }
}

// ---------------- scan_local: fused reduce over u8-packed parts.
__global__ void scan_local(const unsigned* __restrict__ partS,
                           unsigned* __restrict__ partD,
                           unsigned* __restrict__ partP,
                           float* __restrict__ dinv,
                           int* __restrict__ ptr, int* __restrict__ pptr,
                           int* __restrict__ bsumE, int* __restrict__ bsumP, int n)
{
  __shared__ int tmp[256];
  const int i = blockIdx.x * 256 + threadIdx.x;
  const int lane = threadIdx.x & 63;
  unsigned ssum = 0, dtot = 0, ptot = 0;
  if (i < n && (i & 3) == 0) {
    const int c = i >> 2;
    for (int b = 0; b < NB_H; b += 8) {
      unsigned sv[8];
#pragma unroll
      for (int q = 0; q < 8; ++q) sv[q] = partS[(size_t)(b + q) * HW + c];
#pragma unroll
      for (int q = 0; q < 8; ++q) ssum += sv[q];
    }
    unsigned run = 0;
    for (int b = 0; b < NB_H; b += 8) {
      unsigned dv[8];
#pragma unroll
      for (int q = 0; q < 8; ++q) dv[q] = partD[(size_t)(b + q) * HW + c];
#pragma unroll
      for (int q = 0; q < 8; ++q) { const unsigned pre = run; run += dv[q]; dv[q] = pre; }
#pragma unroll
      for (int q = 0; q < 8; ++q) partD[(size_t)(b + q) * HW + c] = dv[q];
    }
    dtot = run;
    unsigned prun = 0;
    for (int b = 0; b < NB_H; b += 8) {
      unsigned pv[8];
#pragma unroll
      for (int q = 0; q < 8; ++q) pv[q] = partP[(size_t)(b + q) * HW + c];
#pragma unroll
      for (int q = 0; q < 8; ++q) { const unsigned pre = prun; prun += pv[q]; pv[q] = pre; }
#pragma unroll
      for (int q = 0; q < 8; ++q) partP[(size_t)(b + q) * HW + c] = pv[q];
    }
    ptot = prun;
  }
  const unsigned sAll = __shfl(ssum, lane & ~3, 64);
  const unsigned dAll = __shfl(dtot, lane & ~3, 64);
  const unsigned pAll = __shfl(ptot, lane & ~3, 64);
  int v = 0, v2 = 0;
  if (i < n) {
    const int hs = (i & 3) * 8;
    const unsigned dg = (sAll >> hs) & 0xffu;
    dinv[i] = dg ? 1.f / sqrtf((float)dg) : 0.f;
    v = (int)((dAll >> hs) & 0xffu);
    v2 = (int)((pAll >> hs) & 0xffu);
  }
  // scan 1: edge counts
  tmp[threadIdx.x] = v;
  __syncthreads();
  for (int off = 1; off < 256; off <<= 1) {
    const int t = (threadIdx.x >= off) ? tmp[threadIdx.x - off] : 0;
    __syncthreads();
    tmp[threadIdx.x] += t;
    __syncthreads();
  }
  if (i < n) ptr[i] = tmp[threadIdx.x] - v;
  if (threadIdx.x == 255) bsumE[blockIdx.x] = tmp[255];
  __syncthreads();
  // scan 2: pair counts
  tmp[threadIdx.x] = v2;
  __syncthreads();
  for (int off = 1; off < 256; off <<= 1) {
    const int t = (threadIdx.x >= off) ? tmp[threadIdx.x - off] : 0;
    __syncthreads();
    tmp[threadIdx.x] += t;
    __syncthreads();
  }
  if (i < n) pptr[i] = tmp[threadIdx.x] - v2;
  if (threadIdx.x == 255) bsumP[blockIdx.x] = tmp[255];
}

__global__ void scan_add2(int* __restrict__ ptr, int* __restrict__ pptr,
                          const int* __restrict__ bsumE, const int* __restrict__ bsumP,
                          int n, int E, int twoP, int nb, float* __restrict__ accs)
{
  __shared__ int tmp[256];
  // edges
  const int v = (threadIdx.x < nb) ? bsumE[threadIdx.x] : 0;
  tmp[threadIdx.x] = v;
  __syncthreads();
  for (int off = 1; off < 256; off <<= 1) {
    const int t = (threadIdx.x >= off) ? tmp[threadIdx.x - off] : 0;
    __syncthreads();
    tmp[threadIdx.x] += t;
    __syncthreads();
  }
  const int offE = (blockIdx.x > 0) ? tmp[blockIdx.x - 1] : 0;
  __syncthreads();
  // pairs
  const int v2 = (threadIdx.x < nb) ? bsumP[threadIdx.x] : 0;
  tmp[threadIdx.x] = v2;
  __syncthreads();
  for (int off = 1; off < 256; off <<= 1) {
    const int t = (threadIdx.x >= off) ? tmp[threadIdx.x - off] : 0;
    __syncthreads();
    tmp[threadIdx.x] += t;
    __syncthreads();
  }
  const int offP = (blockIdx.x > 0) ? tmp[blockIdx.x - 1] : 0;
  const int i = blockIdx.x * 256 + threadIdx.x;
  if (i < n) { ptr[i] += offE; pptr[i] += offP; }
  if (i == 0) {
    ptr[n] = E; pptr[n] = twoP;
    accs[0] = 0.f; accs[1] = 0.f; accs[4] = 0.f;  // accs[4] = loss done-counter
  }
}

// ---------------- atomic-free edge fill (u8 base extract)
__global__ void fill_csr2(const int* __restrict__ src, const int* __restrict__ dst,
                          const float* __restrict__ dinv, const int* __restrict__ ptr,
                          const unsigned* __restrict__ baseD,
                          const ushort_t* __restrict__ rank,
                          int2* __restrict__ csr, int E)
{
  const int e = blockIdx.x * 256 + threadIdx.x;
  if (e >= E) return;
  const int cs = (E + NB_H - 1) / NB_H;
  const int b = e / cs;
  const int s = src[e], d = dst[e];
  const unsigned bv = baseD[(size_t)b * HW + (d >> 2)];
  const int base = (int)((bv >> ((d & 3) * 8)) & 0xffu);
  const int pos = ptr[d] + base + (int)rank[e];
  const float w = -dinv[s] * dinv[d];
  csr[pos] = make_int2(s, __float_as_int(w));
}

#define ACCV(u, ww) { f32x2 t; \
  t = cvt2lo(u.x); a[0]  = fmaf(ww, t.x, a[0]);  a[1]  = fmaf(ww, t.y, a[1]);  \
  t = cvt2hi(u.x); a[2]  = fmaf(ww, t.x, a[2]);  a[3]  = fmaf(ww, t.y, a[3]);  \
  t = cvt2lo(u.y); a[4]  = fmaf(ww, t.x, a[4]);  a[5]  = fmaf(ww, t.y, a[5]);  \
  t = cvt2hi(u.y); a[6]  = fmaf(ww, t.x, a[6]);  a[7]  = fmaf(ww, t.y, a[7]);  \
  t = cvt2lo(u.z); a[8]  = fmaf(ww, t.x, a[8]);  a[9]  = fmaf(ww, t.y, a[9]);  \
  t = cvt2hi(u.z); a[10] = fmaf(ww, t.x, a[10]); a[11] = fmaf(ww, t.y, a[11]); \
  t = cvt2lo(u.w); a[12] = fmaf(ww, t.x, a[12]); a[13] = fmaf(ww, t.y, a[13]); \
  t = cvt2hi(u.w); a[14] = fmaf(ww, t.x, a[14]); a[15] = fmaf(ww, t.y, a[15]); }

// ---------------- gather128: eighth-wave, 8-edge unroll
__global__ __launch_bounds__(256) void gather128e(
    const u8* __restrict__ xf8, ushort_t* __restrict__ txb,
    const int* __restrict__ ptr, const int2* __restrict__ csr, int M)
{
  const int node = (blockIdx.x * 256 + threadIdx.x) >> 3;
  const int sub  = threadIdx.x & 7;
  if (node >= M) return;
  const int beg = ptr[node], end = ptr[node + 1];
  float a[16] = {};
  int p = beg;
  for (; p + 8 <= end; p += 8) {
    int2 e[8];
#pragma unroll
    for (int q = 0; q < 8; ++q) e[q] = csr[p + q];
    uint4 v[8];
#pragma unroll
    for (int q = 0; q < 8; ++q)
      v[q] = *(const uint4*)(xf8 + (size_t)e[q].x * 128 + sub * 16);
#pragma unroll
    for (int q = 0; q < 8; ++q) { const float wq = __int_as_float(e[q].y); ACCV(v[q], wq) }
  }
  for (; p < end; ++p) {
    const int2 eq = csr[p]; const float wq = __int_as_float(eq.y);
    const uint4 v = *(const uint4*)(xf8 + (size_t)eq.x * 128 + sub * 16);
    ACCV(v, wq)
  }
  uint4 o1, o2;
  o1.x = (unsigned)f2bf(a[0])  | ((unsigned)f2bf(a[1])  << 16);
  o1.y = (unsigned)f2bf(a[2])  | ((unsigned)f2bf(a[3])  << 16);
  o1.z = (unsigned)f2bf(a[4])  | ((unsigned)f2bf(a[5])  << 16);
  o1.w = (unsigned)f2bf(a[6])  | ((unsigned)f2bf(a[7])  << 16);
  o2.x = (unsigned)f2bf(a[8])  | ((unsigned)f2bf(a[9])  << 16);
  o2.y = (unsigned)f2bf(a[10]) | ((unsigned)f2bf(a[11]) << 16);
  o2.z = (unsigned)f2bf(a[12]) | ((unsigned)f2bf(a[13]) << 16);
  o2.w = (unsigned)f2bf(a[14]) | ((unsigned)f2bf(a[15]) << 16);
  ushort_t* dstp = txb + (size_t)node * 128 + sub * 16;
  *(uint4*)dstp = o1;
  *(uint4*)(dstp + 8) = o2;
}

// ---------------- fused gather100 + x1 (eighth-wave, 8-edge unroll)
__global__ __launch_bounds__(256) void gather100e_x1(
    const u8* __restrict__ Brh, float* __restrict__ Ar,
    const int* __restrict__ ptr, const int2* __restrict__ csr, int M)
{
  const int node = (blockIdx.x * 256 + threadIdx.x) >> 3;
  const int sub  = threadIdx.x & 7;
  if (node >= M) return;
  const int beg = ptr[node], end = ptr[node + 1];
  float a[16] = {};
  int p = beg;
  for (; p + 8 <= end; p += 8) {
    int2 e[8];
#pragma unroll
    for (int q = 0; q < 8; ++q) e[q] = csr[p + q];
    uint4 v[8];
#pragma unroll
    for (int q = 0; q < 8; ++q)
      v[q] = *(const uint4*)(Brh + (size_t)e[q].x * 128 + sub * 16);
#pragma unroll
    for (int q = 0; q < 8; ++q) { const float wq = __int_as_float(e[q].y); ACCV(v[q], wq) }
  }
  for (; p < end; ++p) {
    const int2 eq = csr[p]; const float wq = __int_as_float(eq.y);
    const uint4 v = *(const uint4*)(Brh + (size_t)eq.x * 128 + sub * 16);
    ACCV(v, wq)
  }
  float* dstp = Ar + (size_t)node * 128 + sub * 16;
#pragma unroll
  for (int q = 0; q < 4; ++q) {
    float4 b = *(const float4*)(dstp + q * 4);
    b.x = fmaxf(b.x + a[q * 4 + 0], 0.f);
    b.y = fmaxf(b.y + a[q * 4 + 1], 0.f);
    b.z = fmaxf(b.z + a[q * 4 + 2], 0.f);
    b.w = fmaxf(b.w + a[q * 4 + 3], 0.f);
    *(float4*)(dstp + q * 4) = b;
  }
}
#undef ACCV

// ---------------- merged gather2 (blocks [0,nbScan), LONGER -> first) + loss
__device__ __forceinline__ void maskrow(uint4& r, int sub) {
  if (sub >= 6) { r.y = 0u; r.z = 0u; r.w = 0u; if (sub == 7) r.x = 0u; }
}
#define DOTA(vv, s) { f32x2 q_; \
  q_ = cvt2lo(vv.x); s = fmaf(af[0],  q_.x, s); s = fmaf(af[1],  q_.y, s); \
  q_ = cvt2hi(vv.x); s = fmaf(af[2],  q_.x, s); s = fmaf(af[3],  q_.y, s); \
  q_ = cvt2lo(vv.y); s = fmaf(af[4],  q_.x, s); s = fmaf(af[5],  q_.y, s); \
  q_ = cvt2hi(vv.y); s = fmaf(af[6],  q_.x, s); s = fmaf(af[7],  q_.y, s); \
  q_ = cvt2lo(vv.z); s = fmaf(af[8],  q_.x, s); s = fmaf(af[9],  q_.y, s); \
  q_ = cvt2hi(vv.z); s = fmaf(af[10], q_.x, s); s = fmaf(af[11], q_.y, s); \
  q_ = cvt2lo(vv.w); s = fmaf(af[12], q_.x, s); s = fmaf(af[13], q_.y, s); \
  q_ = cvt2hi(vv.w); s = fmaf(af[14], q_.x, s); s = fmaf(af[15], q_.y, s); }
#define CVT_AF(ra) { f32x2 t_; \
  t_ = cvt2lo(ra.x); af[0]  = t_.x; af[1]  = t_.y; \
  t_ = cvt2hi(ra.x); af[2]  = t_.x; af[3]  = t_.y; \
  t_ = cvt2lo(ra.y); af[4]  = t_.x; af[5]  = t_.y; \
  t_ = cvt2hi(ra.y); af[6]  = t_.x; af[7]  = t_.y; \
  t_ = cvt2lo(ra.z); af[8]  = t_.x; af[9]  = t_.y; \
  t_ = cvt2hi(ra.z); af[10] = t_.x; af[11] = t_.y; \
  t_ = cvt2lo(ra.w); af[12] = t_.x; af[13] = t_.y; \
  t_ = cvt2hi(ra.w); af[14] = t_.x; af[15] = t_.y; }

__global__ __launch_bounds__(256) void loss_g2(
    const u8* __restrict__ zf8, const int2* __restrict__ psr,
    float* __restrict__ acc,
    const float* __restrict__ t1, const float* __restrict__ t0,
    const int* __restrict__ ptr, const int2* __restrict__ csr,
    float* __restrict__ out, int M, int twoP, int nbScan, int lossNB,
    const float* __restrict__ c1, const float* __restrict__ c2, float invP)
{
  const int tid = threadIdx.x;
  if ((int)blockIdx.x < nbScan) {
    // ---- gather2 section (scheduled first: longer blocks, LPT)
    const int i = blockIdx.x * 256 + tid;
    if (i >= M) return;
    float a0 = 0.f, a1 = 0.f;
    const int beg = ptr[i], end = ptr[i + 1];
    int p = beg;
    for (; p + 4 <= end; p += 4) {
      const int2 e0 = csr[p], e1 = csr[p + 1], e2 = csr[p + 2], e3 = csr[p + 3];
      const float w0 = __int_as_float(e0.y), w1 = __int_as_float(e1.y);
      const float w2 = __int_as_float(e2.y), w3 = __int_as_float(e3.y);
      const float2 v0 = *(const float2*)(t1 + (size_t)e0.x * 2);
      const float2 v1 = *(const float2*)(t1 + (size_t)e1.x * 2);
      const float2 v2 = *(const float2*)(t1 + (size_t)e2.x * 2);
      const float2 v3 = *(const float2*)(t1 + (size_t)e3.x * 2);
      a0 = fmaf(w0, v0.x, a0); a1 = fmaf(w0, v0.y, a1);
      a0 = fmaf(w1, v1.x, a0); a1 = fmaf(w1, v1.y, a1);
      a0 = fmaf(w2, v2.x, a0); a1 = fmaf(w2, v2.y, a1);
      a0 = fmaf(w3, v3.x, a0); a1 = fmaf(w3, v3.y, a1);
    }
    for (; p < end; ++p) {
      const int2 eq = csr[p]; const float wq = __int_as_float(eq.y);
      const float2 v = *(const float2*)(t1 + (size_t)eq.x * 2);
      a0 = fmaf(wq, v.x, a0); a1 = fmaf(wq, v.y, a1);
    }
    const float2 base = *(const float2*)(t0 + (size_t)i * 2);
    *(float2*)(out + (size_t)i * 2) = make_float2(base.x + a0, base.y + a1);
    return;
  }
  // ---- loss: FLAT 16-pair chunks per 8-lane slot (perfect balance).
  __shared__ float red[8];
  const int lane = tid & 63, wib = tid >> 6;
  const int sub = tid & 7;
  const int slot = ((int)blockIdx.x - nbScan) * 32 + (tid >> 3);
  float tp = 0.f, tn = 0.f;
  int p = slot * 16;
  if (p < twoP) {
    const int pend = (p + 16 < twoP) ? p + 16 : twoP;
    int curNa = -1;
    float af[16];
#pragma unroll
    for (int q = 0; q < 16; ++q) af[q] = 0.f;
    for (; p + 4 <= pend; p += 4) {
      int2 pr4[4];
#pragma unroll
      for (int q = 0; q < 4; ++q) pr4[q] = psr[p + q];
      uint4 rb[4];
#pragma unroll
      for (int q = 0; q < 4; ++q) {
        rb[q] = make_uint4(0u, 0u, 0u, 0u);
        const int nv = pr4[q].y & 0x7fffffff;
        if (sub < 7) rb[q] = *(const uint4*)(zf8 + (size_t)nv * 128 + sub * 16);
        maskrow(rb[q], sub);
      }
      float s[4] = {0.f, 0.f, 0.f, 0.f};
#pragma unroll
      for (int q = 0; q < 4; ++q) {
        if (pr4[q].x != curNa) {
          curNa = pr4[q].x;
          uint4 ra = make_uint4(0u, 0u, 0u, 0u);
          if (sub < 7) ra = *(const uint4*)(zf8 + (size_t)curNa * 128 + sub * 16);
          maskrow(ra, sub);
          CVT_AF(ra)
        }
        DOTA(rb[q], s[q])
      }
#pragma unroll
      for (int off = 4; off; off >>= 1) {
#pragma unroll
        for (int q = 0; q < 4; ++q) s[q] += __shfl_down(s[q], off, 8);
      }
      if (sub == 0) {
#pragma unroll
        for (int q = 0; q < 4; ++q) {
          const float sig = 1.f / (1.f + __expf(-s[q]));
          if ((unsigned)pr4[q].y >> 31) tn += __logf(1.f - sig + 1e-15f);
          else tp += __logf(sig + 1e-15f);
        }
      }
    }
    for (; p < pend; ++p) {
      const int2 pr = psr[p];
      const int nv = pr.y & 0x7fffffff;
      uint4 rb = make_uint4(0u, 0u, 0u, 0u);
      if (sub < 7) rb = *(const uint4*)(zf8 + (size_t)nv * 128 + sub * 16);
      maskrow(rb, sub);
      if (pr.x != curNa) {
        curNa = pr.x;
        uint4 ra = make_uint4(0u, 0u, 0u, 0u);
        if (sub < 7) ra = *(const uint4*)(zf8 + (size_t)curNa * 128 + sub * 16);
        maskrow(ra, sub);
        CVT_AF(ra)
      }
      float s = 0.f;
      DOTA(rb, s)
#pragma unroll
      for (int off = 4; off; off >>= 1) s += __shfl_down(s, off, 8);
      if (sub == 0) {
        const float sig = 1.f / (1.f + __expf(-s));
        if ((unsigned)pr.y >> 31) tn += __logf(1.f - sig + 1e-15f);
        else tp += __logf(sig + 1e-15f);
      }
    }
  }
  tp += __shfl_down(tp, 32, 64); tn += __shfl_down(tn, 32, 64);
  tp += __shfl_down(tp, 16, 64); tn += __shfl_down(tn, 16, 64);
  tp += __shfl_down(tp, 8, 64);  tn += __shfl_down(tn, 8, 64);
  if (lane == 0) { red[wib] = tp; red[4 + wib] = tn; }
  __syncthreads();
  if (tid == 0) {
    atomicAdd(acc + 0, red[0] + red[1] + red[2] + red[3]);
    atomicAdd(acc + 1, red[4] + red[5] + red[6] + red[7]);
    __threadfence();
    const unsigned t = atomicAdd((unsigned*)(acc + 4), 1u);
    if (t == (unsigned)(lossNB - 1)) {      // last loss block: final scalars
      __threadfence();
      const float a0 = atomicAdd(acc + 0, 0.f);
      const float a1 = atomicAdd(acc + 1, 0.f);
      out[2 * M + 0] = -(a0 + a1) * invP;
      out[2 * M + 1] = c1[0];
      out[2 * M + 2] = c2[0];
    }
  }
}
#undef DOTA
#undef CVT_AF

extern "C" void kernel_launch(void* const* d_in, const int* in_sizes, int n_in,
                              void* d_out, int out_size, void* d_ws, size_t ws_size,
                              hipStream_t stream)
{
  const float* x   = (const float*)d_in[0];
  const int*   ei  = (const int*)d_in[1];
  const int*   ep  = (const int*)d_in[2];
  const int*   en  = (const int*)d_in[3];
  const float* W1  = (const float*)d_in[4];
  const float* b1  = (const float*)d_in[5];
  const float* W2  = (const float*)d_in[6];
  const float* b2  = (const float*)d_in[7];
  const float* W3  = (const float*)d_in[8];
  const float* b3  = (const float*)d_in[9];
  const float* l1W = (const float*)d_in[10];
  const float* l1b = (const float*)d_in[11];
  const float* l2W = (const float*)d_in[12];
  const float* l2b = (const float*)d_in[13];
  const float* c1  = (const float*)d_in[14];
  const float* c2  = (const float*)d_in[15];
  float* out = (float*)d_out;

  const int M = in_sizes[0] / 128;  // 50000
  const int E = in_sizes[1] / 2;    // 800000
  const int P = in_sizes[2] / 2;    // 400000
  const int* src = ei;
  const int* dst = ei + E;
  const int nb_scan = (M + 255) / 256;
  const int fillE = (E + 255) / 256;
  const int fillP = (2 * P + 255) / 256;
  const int pf0 = fillP / 2;                  // pair-fill blocks on gemm0
  const int pf1 = fillP - pf0;                // pair-fill blocks on gemm1
  const int lossSlots = (2 * P + 15) / 16;
  const int lossNB = (lossSlots + 31) / 32;   // flat-chunk loss blocks

  float* ws = (float*)d_ws;
  size_t o = 0;
  float*    dinv = ws + o;            o += 50176;
  int*      ptr  = (int*)(ws + o);    o += (size_t)M + 8;
  int*      pptr = (int*)(ws + o);    o += (size_t)M + 8;
  int*      bsumE = (int*)(ws + o);   o += 256;
  int*      bsumP = (int*)(ws + o);   o += 256;
  int2*     csr  = (int2*)(ws + o);   o += (size_t)E * 2;
  ushort_t* rank = (ushort_t*)(ws + o); o += (size_t)E / 2;
  int2*     psr  = (int2*)(ws + o);   o += (size_t)4 * P;      // sorted {na, nb|neg}
  ushort_t* xb   = (ushort_t*)(ws + o); o += (size_t)M * 64;   // bf16 [M][128]
  u8*       xf8  = (u8*)(ws + o);     o += (size_t)M * 32;     // fp8 [M][128]
  ushort_t* tx0b = (ushort_t*)(ws + o); o += (size_t)M * 64;   // bf16 [M][128]
  ushort_t* W1t  = (ushort_t*)(ws + o); o += 40960;
  ushort_t* W2t  = (ushort_t*)(ws + o); o += 35840;
  ushort_t* Wlt  = (ushort_t*)(ws + o); o += 14336;
  u8*       h8   = (u8*)(ws + o);     o += (size_t)M * 160;    // 32MB region: GEMM uses front 16MB
  float*    Ar   = ws + o;            o += (size_t)M * 128;    // f32 stride128
  u8*       Brh  = (u8*)(ws + o);     o += (size_t)M * 32;     // fp8 [M][128]
  u8*       zf8  = (u8*)(ws + o);     o += (size_t)M * 32;     // fp8 [M][128]
  float*    t0   = ws + o;            o += (size_t)M * 2;
  float*    t1   = ws + o;            o += (size_t)M * 2;
  float*    accs = ws + o;            o += 8;
  // aliases into regions dead during their live range (u8 parts: 3.2MB each):
  //   partS: h8 front (prep writes, scan_local reads — before gemm0 writes h8)
  //   partD: Ar front (consumed by fill_csr2, before gemm1 writes Ar)
  //   partP/prank: h8 BACK half (GEMM uses only [0, M*320B); back half never
  //     written — safe for gemm1's pair-fill tail which runs while gemm1's
  //     GEMM blocks write Ar)
  unsigned* partS = (unsigned*)h8;
  unsigned* partD = (unsigned*)Ar;
  unsigned* partP = (unsigned*)(h8 + (size_t)M * 320);
  ushort_t* prank = (ushort_t*)(h8 + (size_t)M * 320 + 3200000);

  // prep: src-hist | dst-hist+rank | pair-hist+prank | packing — all input-only
  const int n4 = M * 32;
  const int packBlocks = (n4 + 182272 + 255) / 256;
  prep<<<3 * NB_H + packBlocks, 256, 0, stream>>>(
      src, dst, E, M, partS, partD, rank,
      ep, en, P, partP, prank,
      x, xb, xf8, n4, W1, W2, l1W, l2W, W1t, W2t, Wlt);

  // CSR builds: fused reduce+double-scan -> add -> edge fill only
  scan_local<<<nb_scan, 256, 0, stream>>>(partS, partD, partP, dinv, ptr, pptr,
                                          bsumE, bsumP, M);
  scan_add2<<<nb_scan, 256, 0, stream>>>(ptr, pptr, bsumE, bsumP, M, E, 2 * P,
                                         nb_scan, accs);
  fill_csr2<<<fillE, 256, 0, stream>>>(src, dst, dinv, ptr, partD, rank, csr, E);

  const int gB = (M + 63) / 64;
  const int gE8 = (M * 8 + 255) / 256;

  // conv1 (h out as fp8); gemm0 dispatch carries pair-fill half 1
  gather128e<<<gE8, 256, 0, stream>>>(xf8, tx0b, ptr, csr, M);
  gemm_mfma<0, 320, 256><<<gB + pf0, 256, 0, stream>>>(
      xb, tx0b, W1t, b1, nullptr, nullptr, nullptr, nullptr, h8, nullptr,
      nullptr, nullptr, M, gB, 0, ep, en, P, pptr, partP, prank, psr);

  // conv2 (A = h fp8); gemm1 dispatch carries pair-fill half 2
  gemm_mfma<1, 224, 320><<<gB + pf1, 256, 0, stream>>>(
      (const ushort_t*)h8, nullptr, W2t, b2, nullptr, nullptr, nullptr, nullptr,
      Ar, Brh, nullptr, nullptr, M, gB, pf0 * 256, ep, en, P, pptr, partP,
      prank, psr);
  gather100e_x1<<<gE8, 256, 0, stream>>>(Brh, Ar, ptr, csr, M);

  // lins + fused w3
  gemm_mfma<2, 224, 128><<<gB, 256, 0, stream>>>(
      xb, nullptr, Wlt, l1b, l2b, Ar /*x1*/, W3, b3, nullptr, zf8, t0, t1, M,
      gB, 0, nullptr, nullptr, 0, nullptr, nullptr, nullptr, nullptr);

  // gather2 (first, LPT) || loss (flat-chunk); last loss block emits scalars
  loss_g2<<<nb_scan + lossNB, 256, 0, stream>>>(
      zf8, psr, accs, t1, t0, ptr, csr, out, M, 2 * P, nb_scan, lossNB,
      c1, c2, 1.0f / (float)P);
}

// Round 12
// 434.260 us; speedup vs baseline: 1.0775x; 1.0775x over previous
//
#include <hip/hip_runtime.h>
#include <math.h>

// MTGCN R25 = R24 minus the loss/final-scalars fusion (it raised loss VGPR
// 40->64, occupancy 37->28%, dur 67->91us — a -2us launch saving for -24us
// of occupancy on the latency-hiding-critical kernel). final_scalars is a
// separate launch again; loss_g2 restored to the R23 body.
// KEPT from R24: pair-fill split 50/50 across gemm0+gemm1 tails (R24 top-5
// showed both gemm dispatches dropped below loss's level — split works),
// partP/prank in h8's unused back half.
// KEPT from R23: psr single int2 scatter, flat 16-pair loss chunks, u8
// single-pass histograms, LPT loss dispatch, NB_H=64, fused reduce+scan,
// __expf/__logf + sub<7, fp8 128B rows, h fp8 [M][320], MFMA GEMMs.

typedef unsigned short ushort_t;
typedef unsigned char u8;
typedef __attribute__((ext_vector_type(8))) __bf16 bf16x8;
typedef __attribute__((ext_vector_type(8))) short s16x8;
typedef __attribute__((ext_vector_type(4))) float f32x4;
typedef __attribute__((ext_vector_type(2))) float f32x2;

#define NB_H 64
#define HW 12500   // u32 words; 4 packed u8 counters each -> covers 50000 nodes

__device__ __forceinline__ f32x4 mfma16x16x32(s16x8 a, s16x8 b, f32x4 c) {
  return __builtin_amdgcn_mfma_f32_16x16x32_bf16(
      __builtin_bit_cast(bf16x8, a), __builtin_bit_cast(bf16x8, b), c, 0, 0, 0);
}
__device__ __forceinline__ ushort_t f2bf(float f) {
  union { float f; unsigned u; } c; c.f = f;
  unsigned r = (c.u + 0x7FFFu + ((c.u >> 16) & 1u)) >> 16;
  return (ushort_t)r;
}
__device__ __forceinline__ f32x2 cvt2lo(unsigned u) {
  return __builtin_amdgcn_cvt_pk_f32_fp8((int)u, false);
}
__device__ __forceinline__ f32x2 cvt2hi(unsigned u) {
  return __builtin_amdgcn_cvt_pk_f32_fp8((int)u, true);
}
__device__ __forceinline__ u8 f2fp8(float f) {
  return (u8)(__builtin_amdgcn_cvt_pk_fp8_f32(f, 0.f, 0, false) & 0xff);
}

// =======================================================================
// MFMA GEMM; VAR==0/1 dispatches carry pair-fill tail blocks (>= gemmNB)
// =======================================================================
template<int VAR, int NT, int KTOT>
__global__ __launch_bounds__(256) void gemm_mfma(
    const ushort_t* __restrict__ A0, const ushort_t* __restrict__ A1,
    const ushort_t* __restrict__ Wt,
    const float* __restrict__ bias0, const float* __restrict__ bias1,
    const float* __restrict__ x1,
    const float* __restrict__ W3c, const float* __restrict__ b3c,
    void* __restrict__ out0, void* __restrict__ out1,
    float* __restrict__ t0g, float* __restrict__ t1g, int M,
    int gemmNB, int pfOff,
    const int* __restrict__ ep, const int* __restrict__ en, int P,
    const int* __restrict__ pptr, const unsigned* __restrict__ baseP,
    const ushort_t* __restrict__ prank, int2* __restrict__ psr)
{
  if (VAR != 2 && (int)blockIdx.x >= gemmNB) {
    // ---- pair-fill tail: psr[pos] = {na, nb|negbit}, one 8B scattered store
    const int i = ((int)blockIdx.x - gemmNB) * 256 + (int)threadIdx.x + pfOff;
    const int twoP = 2 * P;
    if (i >= twoP) return;
    const int neg = (i >= P);
    const int p = neg ? i - P : i;
    const int* ia = neg ? en : ep;
    const int na = ia[p], nbv = ia[P + p];
    const int cs2 = (twoP + NB_H - 1) / NB_H;
    const int b = i / cs2;
    const unsigned bv = baseP[(size_t)b * HW + (na >> 2)];
    const int base = (int)((bv >> ((na & 3) * 8)) & 0xffu);
    const int pos = pptr[na] + base + (int)prank[i];
    psr[pos] = make_int2(na, nbv | (neg ? (int)0x80000000 : 0));
    return;
  }
  constexpr int NF = NT / 32;
  __shared__ __align__(16) ushort_t As[64 * 40];
  __shared__ __align__(16) ushort_t Bs[NT * 40];
  __shared__ float w3s[400];
  const int tid  = threadIdx.x;
  const int lane = tid & 63, w = tid >> 6;
  const int m0 = blockIdx.x * 64;
  const int wm = (w & 1) * 32, wn = (w >> 1) * (NT / 2);
  if (VAR == 2) { for (int i = tid; i < 400; i += 256) w3s[i] = W3c[i]; }
  f32x4 acc[2][NF];
#pragma unroll
  for (int i = 0; i < 2; ++i)
#pragma unroll
    for (int j = 0; j < NF; ++j) acc[i][j] = (f32x4){0.f, 0.f, 0.f, 0.f};

  for (int k0 = 0; k0 < KTOT; k0 += 32) {
    { // A stage
      const int r = tid >> 2, c8 = (tid & 3) * 8;
      const int gm = m0 + r;
      uint4 v = {0u, 0u, 0u, 0u};
      if (gm < M) {
        if (VAR == 1) {  // fp8 h: load 8 bytes, convert to 8 bf16
          const u8* s8 = (const u8*)A0 + (size_t)gm * 320 + k0 + c8;
          const uint2 r8 = *(const uint2*)s8;
          const f32x2 f0 = cvt2lo(r8.x), f1 = cvt2hi(r8.x);
          const f32x2 f2 = cvt2lo(r8.y), f3 = cvt2hi(r8.y);
          v.x = (unsigned)f2bf(f0.x) | ((unsigned)f2bf(f0.y) << 16);
          v.y = (unsigned)f2bf(f1.x) | ((unsigned)f2bf(f1.y) << 16);
          v.z = (unsigned)f2bf(f2.x) | ((unsigned)f2bf(f2.y) << 16);
          v.w = (unsigned)f2bf(f3.x) | ((unsigned)f2bf(f3.y) << 16);
        } else {
          const ushort_t* srcp;
          if (VAR == 0) srcp = (k0 < 128) ? A0 + (size_t)gm * 128 + k0 + c8
                                          : A1 + (size_t)gm * 128 + (k0 - 128) + c8;
          else srcp = A0 + (size_t)gm * 128 + k0 + c8;
          v = *(const uint4*)srcp;
        }
      }
      *(uint4*)&As[r * 40 + c8] = v;
    }
    { // B stage
      const int c8 = (tid & 3) * 8;
#pragma unroll
      for (int i = 0; i < (NT * 4 + 255) / 256; ++i) {
        const int r = (tid >> 2) + i * 64;
        if (r < NT)
          *(uint4*)&Bs[r * 40 + c8] = *(const uint4*)(Wt + (size_t)r * KTOT + k0 + c8);
      }
    }
    __syncthreads();
    s16x8 af[2], bfr[NF];
#pragma unroll
    for (int mi = 0; mi < 2; ++mi)
      af[mi] = *(const s16x8*)&As[(wm + mi * 16 + (lane & 15)) * 40 + (lane >> 4) * 8];
#pragma unroll
    for (int ni = 0; ni < NF; ++ni)
      bfr[ni] = *(const s16x8*)&Bs[(wn + ni * 16 + (lane & 15)) * 40 + (lane >> 4) * 8];
#pragma unroll
    for (int mi = 0; mi < 2; ++mi)
#pragma unroll
      for (int ni = 0; ni < NF; ++ni)
        acc[mi][ni] = mfma16x16x32(af[mi], bfr[ni], acc[mi][ni]);
    __syncthreads();
  }

  if (VAR == 2) {
#pragma unroll
    for (int mi = 0; mi < 2; ++mi)
#pragma unroll
      for (int r = 0; r < 4; ++r) {
        const int gRow = m0 + wm + mi * 16 + ((lane >> 4) << 2) + r;
        float p0 = 0.f, p1 = 0.f, p2 = 0.f, p3 = 0.f;
#pragma unroll
        for (int ni = 0; ni < NF; ++ni) {
          const int col = wn + ni * 16 + (lane & 15);
          const float v = acc[mi][ni][r];
          if (gRow < M) {
            if (col < 100) {
              const float x2v = x1[(size_t)gRow * 128 + col] + fmaxf(v + bias0[col], 0.f);
              p0 = fmaf(x2v, w3s[col * 2 + 0], p0);
              p1 = fmaf(x2v, w3s[col * 2 + 1], p1);
              p2 = fmaf(x2v, w3s[200 + col * 2 + 0], p2);
              p3 = fmaf(x2v, w3s[200 + col * 2 + 1], p3);
            } else if (col < 200) {
              const int c = col - 100;
              ((u8*)out1)[(size_t)gRow * 128 + c] =
                  f2fp8(x1[(size_t)gRow * 128 + c] + fmaxf(v + bias1[c], 0.f));
            }
          }
        }
        if (wn == 0) {
#pragma unroll
          for (int off = 8; off; off >>= 1) {
            p0 += __shfl_down(p0, off, 16);
            p1 += __shfl_down(p1, off, 16);
            p2 += __shfl_down(p2, off, 16);
            p3 += __shfl_down(p3, off, 16);
          }
          if ((lane & 15) == 0 && gRow < M) {
            t0g[(size_t)gRow * 2 + 0] = p0 + b3c[0];
            t0g[(size_t)gRow * 2 + 1] = p1 + b3c[1];
            t1g[(size_t)gRow * 2 + 0] = p2;
            t1g[(size_t)gRow * 2 + 1] = p3;
          }
        }
      }
  } else {
#pragma unroll
    for (int mi = 0; mi < 2; ++mi)
#pragma unroll
      for (int ni = 0; ni < NF; ++ni)
#pragma unroll
        for (int r = 0; r < 4; ++r) {
          const int gRow = m0 + wm + mi * 16 + ((lane >> 4) << 2) + r;
          const int col  = wn + ni * 16 + (lane & 15);
          if (gRow >= M) continue;
          const float v = acc[mi][ni][r];
          if (VAR == 0) {
            ((u8*)out0)[(size_t)gRow * 320 + col] =
                (col < 300) ? f2fp8(fmaxf(v + bias0[col], 0.f)) : (u8)0;
          } else {
            if (col < 100) ((float*)out0)[(size_t)gRow * 128 + col] = v + bias0[col];
            else if (col < 200) ((u8*)out1)[(size_t)gRow * 128 + (col - 100)] = f2fp8(v);
          }
        }
  }
}

// =======================================================================
// prep: src-hist [0,64) | dst-hist+rank [64,128) | pair-hist+prank [128,192)
//       | packing (rest).  Single-pass u8 histograms (4 per u32 word).
// =======================================================================
__global__ __launch_bounds__(256) void prep(
    const int* __restrict__ src, const int* __restrict__ dst, int E, int M,
    unsigned* __restrict__ partS, unsigned* __restrict__ partD,
    ushort_t* __restrict__ rank,
    const int* __restrict__ ep, const int* __restrict__ en, int P,
    unsigned* __restrict__ partP, ushort_t* __restrict__ prank,
    const float* __restrict__ x, ushort_t* __restrict__ xb,
    u8* __restrict__ xf8, int n4,
    const float* __restrict__ W1, const float* __restrict__ W2,
    const float* __restrict__ l1W, const float* __restrict__ l2W,
    ushort_t* __restrict__ W1t, ushort_t* __restrict__ W2t,
    ushort_t* __restrict__ Wlt)
{
  __shared__ unsigned hist[HW];
  const int blk = blockIdx.x;
  if (blk < 2 * NB_H) {
    const int isD = (blk >= NB_H);
    const int b = isD ? blk - NB_H : blk;
    const int* keys = isD ? dst : src;
    unsigned* part = isD ? partD : partS;
    const int cs = (E + NB_H - 1) / NB_H;
    const int e0 = b * cs;
    const int e1 = (e0 + cs < E) ? e0 + cs : E;
    for (int i = threadIdx.x; i < HW; i += 256) hist[i] = 0;
    __syncthreads();
    for (int e = e0 + threadIdx.x; e < e1; e += 256) {
      const int k = keys[e];
      const unsigned old = atomicAdd(&hist[k >> 2], 1u << ((k & 3) * 8));
      if (isD) rank[e] = (ushort_t)((old >> ((k & 3) * 8)) & 0xffu);
    }
    __syncthreads();
    for (int i = threadIdx.x; i < HW; i += 256)
      part[(size_t)b * HW + i] = hist[i];
    return;
  }
  if (blk < 3 * NB_H) {
    // pair-hist keyed by first endpoint na over index space [0, 2P)
    const int b = blk - 2 * NB_H;
    const int twoP = 2 * P;
    const int cs2 = (twoP + NB_H - 1) / NB_H;
    const int e0 = b * cs2;
    const int e1 = (e0 + cs2 < twoP) ? e0 + cs2 : twoP;
    for (int i = threadIdx.x; i < HW; i += 256) hist[i] = 0;
    __syncthreads();
    for (int i = e0 + threadIdx.x; i < e1; i += 256) {
      const int neg = (i >= P);
      const int p = neg ? i - P : i;
      const int* ia = neg ? en : ep;
      const int k = ia[p];
      const unsigned old = atomicAdd(&hist[k >> 2], 1u << ((k & 3) * 8));
      prank[i] = (ushort_t)((old >> ((k & 3) * 8)) & 0xffu);
    }
    __syncthreads();
    for (int i = threadIdx.x; i < HW; i += 256)
      partP[(size_t)b * HW + i] = hist[i];
    return;
  }
  // packing section
  const int i = (blk - 3 * NB_H) * 256 + threadIdx.x;
  if (i < n4) {
    const float4 v = ((const float4*)x)[i];
    ushort4 o; o.x = f2bf(v.x); o.y = f2bf(v.y); o.z = f2bf(v.z); o.w = f2bf(v.w);
    ((ushort4*)xb)[i] = o;
    int p = 0;
    p = __builtin_amdgcn_cvt_pk_fp8_f32(v.x, v.y, p, false);
    p = __builtin_amdgcn_cvt_pk_fp8_f32(v.z, v.w, p, true);
    ((unsigned*)xf8)[i] = (unsigned)p;
    return;
  }
  const int j = i - n4;
  if (j < 81920) {                       // W1t [320][256]
    const int n = j >> 8, k = j & 255;
    float v = 0.f;
    if (n < 300) v = (k < 128) ? W1[k * 300 + n] : W1[38400 + (k - 128) * 300 + n];
    W1t[j] = f2bf(v);
  } else if (j < 153600) {               // W2t [224][320]
    const int jj = j - 81920;
    const int n = jj / 320, k = jj - n * 320;
    float v = 0.f;
    if (n < 200 && k < 300) v = W2[(n < 100 ? 0 : 30000) + k * 100 + (n % 100)];
    W2t[jj] = f2bf(v);
  } else if (j < 182272) {               // Wlt [224][128]
    const int jj = j - 153600;
    const int n = jj >> 7, k = jj & 127;
    float v = 0.f;
    if (n < 100) v = l1W[n * 128 + k];
    else if (n < 200) v = l2W[(n - 100) * 128 + k];
    Wlt[jj] = f2bf(v);
  }
}

// ---------------- scan_local: fused reduce over u8-packed parts.
__global__ void scan_local(const unsigned* __restrict__ partS,
                           unsigned* __restrict__ partD,
                           unsigned* __restrict__ partP,
                           float* __restrict__ dinv,
                           int* __restrict__ ptr, int* __restrict__ pptr,
                           int* __restrict__ bsumE, int* __restrict__ bsumP, int n)
{
  __shared__ int tmp[256];
  const int i = blockIdx.x * 256 + threadIdx.x;
  const int lane = threadIdx.x & 63;
  unsigned ssum = 0, dtot = 0, ptot = 0;
  if (i < n && (i & 3) == 0) {
    const int c = i >> 2;
    for (int b = 0; b < NB_H; b += 8) {
      unsigned sv[8];
#pragma unroll
      for (int q = 0; q < 8; ++q) sv[q] = partS[(size_t)(b + q) * HW + c];
#pragma unroll
      for (int q = 0; q < 8; ++q) ssum += sv[q];
    }
    unsigned run = 0;
    for (int b = 0; b < NB_H; b += 8) {
      unsigned dv[8];
#pragma unroll
      for (int q = 0; q < 8; ++q) dv[q] = partD[(size_t)(b + q) * HW + c];
#pragma unroll
      for (int q = 0; q < 8; ++q) { const unsigned pre = run; run += dv[q]; dv[q] = pre; }
#pragma unroll
      for (int q = 0; q < 8; ++q) partD[(size_t)(b + q) * HW + c] = dv[q];
    }
    dtot = run;
    unsigned prun = 0;
    for (int b = 0; b < NB_H; b += 8) {
      unsigned pv[8];
#pragma unroll
      for (int q = 0; q < 8; ++q) pv[q] = partP[(size_t)(b + q) * HW + c];
#pragma unroll
      for (int q = 0; q < 8; ++q) { const unsigned pre = prun; prun += pv[q]; pv[q] = pre; }
#pragma unroll
      for (int q = 0; q < 8; ++q) partP[(size_t)(b + q) * HW + c] = pv[q];
    }
    ptot = prun;
  }
  const unsigned sAll = __shfl(ssum, lane & ~3, 64);
  const unsigned dAll = __shfl(dtot, lane & ~3, 64);
  const unsigned pAll = __shfl(ptot, lane & ~3, 64);
  int v = 0, v2 = 0;
  if (i < n) {
    const int hs = (i & 3) * 8;
    const unsigned dg = (sAll >> hs) & 0xffu;
    dinv[i] = dg ? 1.f / sqrtf((float)dg) : 0.f;
    v = (int)((dAll >> hs) & 0xffu);
    v2 = (int)((pAll >> hs) & 0xffu);
  }
  // scan 1: edge counts
  tmp[threadIdx.x] = v;
  __syncthreads();
  for (int off = 1; off < 256; off <<= 1) {
    const int t = (threadIdx.x >= off) ? tmp[threadIdx.x - off] : 0;
    __syncthreads();
    tmp[threadIdx.x] += t;
    __syncthreads();
  }
  if (i < n) ptr[i] = tmp[threadIdx.x] - v;
  if (threadIdx.x == 255) bsumE[blockIdx.x] = tmp[255];
  __syncthreads();
  // scan 2: pair counts
  tmp[threadIdx.x] = v2;
  __syncthreads();
  for (int off = 1; off < 256; off <<= 1) {
    const int t = (threadIdx.x >= off) ? tmp[threadIdx.x - off] : 0;
    __syncthreads();
    tmp[threadIdx.x] += t;
    __syncthreads();
  }
  if (i < n) pptr[i] = tmp[threadIdx.x] - v2;
  if (threadIdx.x == 255) bsumP[blockIdx.x] = tmp[255];
}

__global__ void scan_add2(int* __restrict__ ptr, int* __restrict__ pptr,
                          const int* __restrict__ bsumE, const int* __restrict__ bsumP,
                          int n, int E, int twoP, int nb, float* __restrict__ accs)
{
  __shared__ int tmp[256];
  // edges
  const int v = (threadIdx.x < nb) ? bsumE[threadIdx.x] : 0;
  tmp[threadIdx.x] = v;
  __syncthreads();
  for (int off = 1; off < 256; off <<= 1) {
    const int t = (threadIdx.x >= off) ? tmp[threadIdx.x - off] : 0;
    __syncthreads();
    tmp[threadIdx.x] += t;
    __syncthreads();
  }
  const int offE = (blockIdx.x > 0) ? tmp[blockIdx.x - 1] : 0;
  __syncthreads();
  // pairs
  const int v2 = (threadIdx.x < nb) ? bsumP[threadIdx.x] : 0;
  tmp[threadIdx.x] = v2;
  __syncthreads();
  for (int off = 1; off < 256; off <<= 1) {
    const int t = (threadIdx.x >= off) ? tmp[threadIdx.x - off] : 0;
    __syncthreads();
    tmp[threadIdx.x] += t;
    __syncthreads();
  }
  const int offP = (blockIdx.x > 0) ? tmp[blockIdx.x - 1] : 0;
  const int i = blockIdx.x * 256 + threadIdx.x;
  if (i < n) { ptr[i] += offE; pptr[i] += offP; }
  if (i == 0) { ptr[n] = E; pptr[n] = twoP; accs[0] = 0.f; accs[1] = 0.f; }
}

// ---------------- atomic-free edge fill (u8 base extract)
__global__ void fill_csr2(const int* __restrict__ src, const int* __restrict__ dst,
                          const float* __restrict__ dinv, const int* __restrict__ ptr,
                          const unsigned* __restrict__ baseD,
                          const ushort_t* __restrict__ rank,
                          int2* __restrict__ csr, int E)
{
  const int e = blockIdx.x * 256 + threadIdx.x;
  if (e >= E) return;
  const int cs = (E + NB_H - 1) / NB_H;
  const int b = e / cs;
  const int s = src[e], d = dst[e];
  const unsigned bv = baseD[(size_t)b * HW + (d >> 2)];
  const int base = (int)((bv >> ((d & 3) * 8)) & 0xffu);
  const int pos = ptr[d] + base + (int)rank[e];
  const float w = -dinv[s] * dinv[d];
  csr[pos] = make_int2(s, __float_as_int(w));
}

#define ACCV(u, ww) { f32x2 t; \
  t = cvt2lo(u.x); a[0]  = fmaf(ww, t.x, a[0]);  a[1]  = fmaf(ww, t.y, a[1]);  \
  t = cvt2hi(u.x); a[2]  = fmaf(ww, t.x, a[2]);  a[3]  = fmaf(ww, t.y, a[3]);  \
  t = cvt2lo(u.y); a[4]  = fmaf(ww, t.x, a[4]);  a[5]  = fmaf(ww, t.y, a[5]);  \
  t = cvt2hi(u.y); a[6]  = fmaf(ww, t.x, a[6]);  a[7]  = fmaf(ww, t.y, a[7]);  \
  t = cvt2lo(u.z); a[8]  = fmaf(ww, t.x, a[8]);  a[9]  = fmaf(ww, t.y, a[9]);  \
  t = cvt2hi(u.z); a[10] = fmaf(ww, t.x, a[10]); a[11] = fmaf(ww, t.y, a[11]); \
  t = cvt2lo(u.w); a[12] = fmaf(ww, t.x, a[12]); a[13] = fmaf(ww, t.y, a[13]); \
  t = cvt2hi(u.w); a[14] = fmaf(ww, t.x, a[14]); a[15] = fmaf(ww, t.y, a[15]); }

// ---------------- gather128: eighth-wave, 8-edge unroll
__global__ __launch_bounds__(256) void gather128e(
    const u8* __restrict__ xf8, ushort_t* __restrict__ txb,
    const int* __restrict__ ptr, const int2* __restrict__ csr, int M)
{
  const int node = (blockIdx.x * 256 + threadIdx.x) >> 3;
  const int sub  = threadIdx.x & 7;
  if (node >= M) return;
  const int beg = ptr[node], end = ptr[node + 1];
  float a[16] = {};
  int p = beg;
  for (; p + 8 <= end; p += 8) {
    int2 e[8];
#pragma unroll
    for (int q = 0; q < 8; ++q) e[q] = csr[p + q];
    uint4 v[8];
#pragma unroll
    for (int q = 0; q < 8; ++q)
      v[q] = *(const uint4*)(xf8 + (size_t)e[q].x * 128 + sub * 16);
#pragma unroll
    for (int q = 0; q < 8; ++q) { const float wq = __int_as_float(e[q].y); ACCV(v[q], wq) }
  }
  for (; p < end; ++p) {
    const int2 eq = csr[p]; const float wq = __int_as_float(eq.y);
    const uint4 v = *(const uint4*)(xf8 + (size_t)eq.x * 128 + sub * 16);
    ACCV(v, wq)
  }
  uint4 o1, o2;
  o1.x = (unsigned)f2bf(a[0])  | ((unsigned)f2bf(a[1])  << 16);
  o1.y = (unsigned)f2bf(a[2])  | ((unsigned)f2bf(a[3])  << 16);
  o1.z = (unsigned)f2bf(a[4])  | ((unsigned)f2bf(a[5])  << 16);
  o1.w = (unsigned)f2bf(a[6])  | ((unsigned)f2bf(a[7])  << 16);
  o2.x = (unsigned)f2bf(a[8])  | ((unsigned)f2bf(a[9])  << 16);
  o2.y = (unsigned)f2bf(a[10]) | ((unsigned)f2bf(a[11]) << 16);
  o2.z = (unsigned)f2bf(a[12]) | ((unsigned)f2bf(a[13]) << 16);
  o2.w = (unsigned)f2bf(a[14]) | ((unsigned)f2bf(a[15]) << 16);
  ushort_t* dstp = txb + (size_t)node * 128 + sub * 16;
  *(uint4*)dstp = o1;
  *(uint4*)(dstp + 8) = o2;
}

// ---------------- fused gather100 + x1 (eighth-wave, 8-edge unroll)
__global__ __launch_bounds__(256) void gather100e_x1(
    const u8* __restrict__ Brh, float* __restrict__ Ar,
    const int* __restrict__ ptr, const int2* __restrict__ csr, int M)
{
  const int node = (blockIdx.x * 256 + threadIdx.x) >> 3;
  const int sub  = threadIdx.x & 7;
  if (node >= M) return;
  const int beg = ptr[node], end = ptr[node + 1];
  float a[16] = {};
  int p = beg;
  for (; p + 8 <= end; p += 8) {
    int2 e[8];
#pragma unroll
    for (int q = 0; q < 8; ++q) e[q] = csr[p + q];
    uint4 v[8];
#pragma unroll
    for (int q = 0; q < 8; ++q)
      v[q] = *(const uint4*)(Brh + (size_t)e[q].x * 128 + sub * 16);
#pragma unroll
    for (int q = 0; q < 8; ++q) { const float wq = __int_as_float(e[q].y); ACCV(v[q], wq) }
  }
  for (; p < end; ++p) {
    const int2 eq = csr[p]; const float wq = __int_as_float(eq.y);
    const uint4 v = *(const uint4*)(Brh + (size_t)eq.x * 128 + sub * 16);
    ACCV(v, wq)
  }
  float* dstp = Ar + (size_t)node * 128 + sub * 16;
#pragma unroll
  for (int q = 0; q < 4; ++q) {
    float4 b = *(const float4*)(dstp + q * 4);
    b.x = fmaxf(b.x + a[q * 4 + 0], 0.f);
    b.y = fmaxf(b.y + a[q * 4 + 1], 0.f);
    b.z = fmaxf(b.z + a[q * 4 + 2], 0.f);
    b.w = fmaxf(b.w + a[q * 4 + 3], 0.f);
    *(float4*)(dstp + q * 4) = b;
  }
}
#undef ACCV

// ---------------- merged gather2 (blocks [0,nbScan), LONGER -> first) + loss
__device__ __forceinline__ void maskrow(uint4& r, int sub) {
  if (sub >= 6) { r.y = 0u; r.z = 0u; r.w = 0u; if (sub == 7) r.x = 0u; }
}
#define DOTA(vv, s) { f32x2 q_; \
  q_ = cvt2lo(vv.x); s = fmaf(af[0],  q_.x, s); s = fmaf(af[1],  q_.y, s); \
  q_ = cvt2hi(vv.x); s = fmaf(af[2],  q_.x, s); s = fmaf(af[3],  q_.y, s); \
  q_ = cvt2lo(vv.y); s = fmaf(af[4],  q_.x, s); s = fmaf(af[5],  q_.y, s); \
  q_ = cvt2hi(vv.y); s = fmaf(af[6],  q_.x, s); s = fmaf(af[7],  q_.y, s); \
  q_ = cvt2lo(vv.z); s = fmaf(af[8],  q_.x, s); s = fmaf(af[9],  q_.y, s); \
  q_ = cvt2hi(vv.z); s = fmaf(af[10], q_.x, s); s = fmaf(af[11], q_.y, s); \
  q_ = cvt2lo(vv.w); s = fmaf(af[12], q_.x, s); s = fmaf(af[13], q_.y, s); \
  q_ = cvt2hi(vv.w); s = fmaf(af[14], q_.x, s); s = fmaf(af[15], q_.y, s); }
#define CVT_AF(ra) { f32x2 t_; \
  t_ = cvt2lo(ra.x); af[0]  = t_.x; af[1]  = t_.y; \
  t_ = cvt2hi(ra.x); af[2]  = t_.x; af[3]  = t_.y; \
  t_ = cvt2lo(ra.y); af[4]  = t_.x; af[5]  = t_.y; \
  t_ = cvt2hi(ra.y); af[6]  = t_.x; af[7]  = t_.y; \
  t_ = cvt2lo(ra.z); af[8]  = t_.x; af[9]  = t_.y; \
  t_ = cvt2hi(ra.z); af[10] = t_.x; af[11] = t_.y; \
  t_ = cvt2lo(ra.w); af[12] = t_.x; af[13] = t_.y; \
  t_ = cvt2hi(ra.w); af[14] = t_.x; af[15] = t_.y; }

__global__ __launch_bounds__(256) void loss_g2(
    const u8* __restrict__ zf8, const int2* __restrict__ psr,
    float* __restrict__ acc,
    const float* __restrict__ t1, const float* __restrict__ t0,
    const int* __restrict__ ptr, const int2* __restrict__ csr,
    float* __restrict__ out, int M, int twoP, int nbScan)
{
  const int tid = threadIdx.x;
  if ((int)blockIdx.x < nbScan) {
    // ---- gather2 section (scheduled first: longer blocks, LPT)
    const int i = blockIdx.x * 256 + tid;
    if (i >= M) return;
    float a0 = 0.f, a1 = 0.f;
    const int beg = ptr[i], end = ptr[i + 1];
    int p = beg;
    for (; p + 4 <= end; p += 4) {
      const int2 e0 = csr[p], e1 = csr[p + 1], e2 = csr[p + 2], e3 = csr[p + 3];
      const float w0 = __int_as_float(e0.y), w1 = __int_as_float(e1.y);
      const float w2 = __int_as_float(e2.y), w3 = __int_as_float(e3.y);
      const float2 v0 = *(const float2*)(t1 + (size_t)e0.x * 2);
      const float2 v1 = *(const float2*)(t1 + (size_t)e1.x * 2);
      const float2 v2 = *(const float2*)(t1 + (size_t)e2.x * 2);
      const float2 v3 = *(const float2*)(t1 + (size_t)e3.x * 2);
      a0 = fmaf(w0, v0.x, a0); a1 = fmaf(w0, v0.y, a1);
      a0 = fmaf(w1, v1.x, a0); a1 = fmaf(w1, v1.y, a1);
      a0 = fmaf(w2, v2.x, a0); a1 = fmaf(w2, v2.y, a1);
      a0 = fmaf(w3, v3.x, a0); a1 = fmaf(w3, v3.y, a1);
    }
    for (; p < end; ++p) {
      const int2 eq = csr[p]; const float wq = __int_as_float(eq.y);
      const float2 v = *(const float2*)(t1 + (size_t)eq.x * 2);
      a0 = fmaf(wq, v.x, a0); a1 = fmaf(wq, v.y, a1);
    }
    const float2 base = *(const float2*)(t0 + (size_t)i * 2);
    *(float2*)(out + (size_t)i * 2) = make_float2(base.x + a0, base.y + a1);
    return;
  }
  // ---- loss: FLAT 16-pair chunks per 8-lane slot (perfect balance).
  //      pairs na-sorted -> ra (af regs) reloaded only on na change (~2/chunk)
  __shared__ float red[8];
  const int lane = tid & 63, wib = tid >> 6;
  const int sub = tid & 7;
  const int slot = ((int)blockIdx.x - nbScan) * 32 + (tid >> 3);
  float tp = 0.f, tn = 0.f;
  int p = slot * 16;
  if (p < twoP) {
    const int pend = (p + 16 < twoP) ? p + 16 : twoP;
    int curNa = -1;
    float af[16];
#pragma unroll
    for (int q = 0; q < 16; ++q) af[q] = 0.f;
    for (; p + 4 <= pend; p += 4) {
      int2 pr4[4];
#pragma unroll
      for (int q = 0; q < 4; ++q) pr4[q] = psr[p + q];
      uint4 rb[4];
#pragma unroll
      for (int q = 0; q < 4; ++q) {
        rb[q] = make_uint4(0u, 0u, 0u, 0u);
        const int nv = pr4[q].y & 0x7fffffff;
        if (sub < 7) rb[q] = *(const uint4*)(zf8 + (size_t)nv * 128 + sub * 16);
        maskrow(rb[q], sub);
      }
      float s[4] = {0.f, 0.f, 0.f, 0.f};
#pragma unroll
      for (int q = 0; q < 4; ++q) {
        if (pr4[q].x != curNa) {
          curNa = pr4[q].x;
          uint4 ra = make_uint4(0u, 0u, 0u, 0u);
          if (sub < 7) ra = *(const uint4*)(zf8 + (size_t)curNa * 128 + sub * 16);
          maskrow(ra, sub);
          CVT_AF(ra)
        }
        DOTA(rb[q], s[q])
      }
#pragma unroll
      for (int off = 4; off; off >>= 1) {
#pragma unroll
        for (int q = 0; q < 4; ++q) s[q] += __shfl_down(s[q], off, 8);
      }
      if (sub == 0) {
#pragma unroll
        for (int q = 0; q < 4; ++q) {
          const float sig = 1.f / (1.f + __expf(-s[q]));
          if ((unsigned)pr4[q].y >> 31) tn += __logf(1.f - sig + 1e-15f);
          else tp += __logf(sig + 1e-15f);
        }
      }
    }
    for (; p < pend; ++p) {
      const int2 pr = psr[p];
      const int nv = pr.y & 0x7fffffff;
      uint4 rb = make_uint4(0u, 0u, 0u, 0u);
      if (sub < 7) rb = *(const uint4*)(zf8 + (size_t)nv * 128 + sub * 16);
      maskrow(rb, sub);
      if (pr.x != curNa) {
        curNa = pr.x;
        uint4 ra = make_uint4(0u, 0u, 0u, 0u);
        if (sub < 7) ra = *(const uint4*)(zf8 + (size_t)curNa * 128 + sub * 16);
        maskrow(ra, sub);
        CVT_AF(ra)
      }
      float s = 0.f;
      DOTA(rb, s)
#pragma unroll
      for (int off = 4; off; off >>= 1) s += __shfl_down(s, off, 8);
      if (sub == 0) {
        const float sig = 1.f / (1.f + __expf(-s));
        if ((unsigned)pr.y >> 31) tn += __logf(1.f - sig + 1e-15f);
        else tp += __logf(sig + 1e-15f);
      }
    }
  }
  tp += __shfl_down(tp, 32, 64); tn += __shfl_down(tn, 32, 64);
  tp += __shfl_down(tp, 16, 64); tn += __shfl_down(tn, 16, 64);
  tp += __shfl_down(tp, 8, 64);  tn += __shfl_down(tn, 8, 64);
  if (lane == 0) { red[wib] = tp; red[4 + wib] = tn; }
  __syncthreads();
  if (tid == 0) {
    atomicAdd(acc + 0, red[0] + red[1] + red[2] + red[3]);
    atomicAdd(acc + 1, red[4] + red[5] + red[6] + red[7]);
  }
}
#undef DOTA
#undef CVT_AF

// ---------------- final scalars (needs accs complete)
__global__ void final_scalars(const float* __restrict__ accs,
                              const float* __restrict__ c1, const float* __restrict__ c2,
                              float* __restrict__ out, int M, float invP)
{
  out[2 * M + 0] = -(accs[0] + accs[1]) * invP;
  out[2 * M + 1] = c1[0];
  out[2 * M + 2] = c2[0];
}

extern "C" void kernel_launch(void* const* d_in, const int* in_sizes, int n_in,
                              void* d_out, int out_size, void* d_ws, size_t ws_size,
                              hipStream_t stream)
{
  const float* x   = (const float*)d_in[0];
  const int*   ei  = (const int*)d_in[1];
  const int*   ep  = (const int*)d_in[2];
  const int*   en  = (const int*)d_in[3];
  const float* W1  = (const float*)d_in[4];
  const float* b1  = (const float*)d_in[5];
  const float* W2  = (const float*)d_in[6];
  const float* b2  = (const float*)d_in[7];
  const float* W3  = (const float*)d_in[8];
  const float* b3  = (const float*)d_in[9];
  const float* l1W = (const float*)d_in[10];
  const float* l1b = (const float*)d_in[11];
  const float* l2W = (const float*)d_in[12];
  const float* l2b = (const float*)d_in[13];
  const float* c1  = (const float*)d_in[14];
  const float* c2  = (const float*)d_in[15];
  float* out = (float*)d_out;

  const int M = in_sizes[0] / 128;  // 50000
  const int E = in_sizes[1] / 2;    // 800000
  const int P = in_sizes[2] / 2;    // 400000
  const int* src = ei;
  const int* dst = ei + E;
  const int nb_scan = (M + 255) / 256;
  const int fillE = (E + 255) / 256;
  const int fillP = (2 * P + 255) / 256;
  const int pf0 = fillP / 2;                  // pair-fill blocks on gemm0
  const int pf1 = fillP - pf0;                // pair-fill blocks on gemm1
  const int lossSlots = (2 * P + 15) / 16;
  const int lossNB = (lossSlots + 31) / 32;   // flat-chunk loss blocks

  float* ws = (float*)d_ws;
  size_t o = 0;
  float*    dinv = ws + o;            o += 50176;
  int*      ptr  = (int*)(ws + o);    o += (size_t)M + 8;
  int*      pptr = (int*)(ws + o);    o += (size_t)M + 8;
  int*      bsumE = (int*)(ws + o);   o += 256;
  int*      bsumP = (int*)(ws + o);   o += 256;
  int2*     csr  = (int2*)(ws + o);   o += (size_t)E * 2;
  ushort_t* rank = (ushort_t*)(ws + o); o += (size_t)E / 2;
  int2*     psr  = (int2*)(ws + o);   o += (size_t)4 * P;      // sorted {na, nb|neg}
  ushort_t* xb   = (ushort_t*)(ws + o); o += (size_t)M * 64;   // bf16 [M][128]
  u8*       xf8  = (u8*)(ws + o);     o += (size_t)M * 32;     // fp8 [M][128]
  ushort_t* tx0b = (ushort_t*)(ws + o); o += (size_t)M * 64;   // bf16 [M][128]
  ushort_t* W1t  = (ushort_t*)(ws + o); o += 40960;
  ushort_t* W2t  = (ushort_t*)(ws + o); o += 35840;
  ushort_t* Wlt  = (ushort_t*)(ws + o); o += 14336;
  u8*       h8   = (u8*)(ws + o);     o += (size_t)M * 160;    // 32MB region: GEMM uses front 16MB
  float*    Ar   = ws + o;            o += (size_t)M * 128;    // f32 stride128
  u8*       Brh  = (u8*)(ws + o);     o += (size_t)M * 32;     // fp8 [M][128]
  u8*       zf8  = (u8*)(ws + o);     o += (size_t)M * 32;     // fp8 [M][128]
  float*    t0   = ws + o;            o += (size_t)M * 2;
  float*    t1   = ws + o;            o += (size_t)M * 2;
  float*    accs = ws + o;            o += 8;
  // aliases into regions dead during their live range (u8 parts: 3.2MB each):
  //   partS: h8 front (prep writes, scan_local reads — before gemm0 writes h8)
  //   partD: Ar front (consumed by fill_csr2, before gemm1 writes Ar)
  //   partP/prank: h8 BACK half (GEMM uses only [0, M*320B); back half never
  //     written — safe for gemm1's pair-fill tail which runs while gemm1's
  //     GEMM blocks write Ar)
  unsigned* partS = (unsigned*)h8;
  unsigned* partD = (unsigned*)Ar;
  unsigned* partP = (unsigned*)(h8 + (size_t)M * 320);
  ushort_t* prank = (ushort_t*)(h8 + (size_t)M * 320 + 3200000);

  // prep: src-hist | dst-hist+rank | pair-hist+prank | packing — all input-only
  const int n4 = M * 32;
  const int packBlocks = (n4 + 182272 + 255) / 256;
  prep<<<3 * NB_H + packBlocks, 256, 0, stream>>>(
      src, dst, E, M, partS, partD, rank,
      ep, en, P, partP, prank,
      x, xb, xf8, n4, W1, W2, l1W, l2W, W1t, W2t, Wlt);

  // CSR builds: fused reduce+double-scan -> add -> edge fill only
  scan_local<<<nb_scan, 256, 0, stream>>>(partS, partD, partP, dinv, ptr, pptr,
                                          bsumE, bsumP, M);
  scan_add2<<<nb_scan, 256, 0, stream>>>(ptr, pptr, bsumE, bsumP, M, E, 2 * P,
                                         nb_scan, accs);
  fill_csr2<<<fillE, 256, 0, stream>>>(src, dst, dinv, ptr, partD, rank, csr, E);

  const int gB = (M + 63) / 64;
  const int gE8 = (M * 8 + 255) / 256;

  // conv1 (h out as fp8); gemm0 dispatch carries pair-fill half 1
  gather128e<<<gE8, 256, 0, stream>>>(xf8, tx0b, ptr, csr, M);
  gemm_mfma<0, 320, 256><<<gB + pf0, 256, 0, stream>>>(
      xb, tx0b, W1t, b1, nullptr, nullptr, nullptr, nullptr, h8, nullptr,
      nullptr, nullptr, M, gB, 0, ep, en, P, pptr, partP, prank, psr);

  // conv2 (A = h fp8); gemm1 dispatch carries pair-fill half 2
  gemm_mfma<1, 224, 320><<<gB + pf1, 256, 0, stream>>>(
      (const ushort_t*)h8, nullptr, W2t, b2, nullptr, nullptr, nullptr, nullptr,
      Ar, Brh, nullptr, nullptr, M, gB, pf0 * 256, ep, en, P, pptr, partP,
      prank, psr);
  gather100e_x1<<<gE8, 256, 0, stream>>>(Brh, Ar, ptr, csr, M);

  // lins + fused w3
  gemm_mfma<2, 224, 128><<<gB, 256, 0, stream>>>(
      xb, nullptr, Wlt, l1b, l2b, Ar /*x1*/, W3, b3, nullptr, zf8, t0, t1, M,
      gB, 0, nullptr, nullptr, 0, nullptr, nullptr, nullptr, nullptr);

  // gather2 (first, LPT) || loss (flat-chunk pair-CSR), then scalars
  loss_g2<<<nb_scan + lossNB, 256, 0, stream>>>(
      zf8, psr, accs, t1, t0, ptr, csr, out, M, 2 * P, nb_scan);
  final_scalars<<<1, 1, 0, stream>>>(accs, c1, c2, out, M, 1.0f / (float)P);
}